// Round 3
// baseline (2664.393 us; speedup 1.0000x reference)
//
#include <hip/hip_runtime.h>
#include <math.h>

#define BB 8
#define SS 1024
#define DM 512
#define DK 64
#define NITER 40
#define SPARS 0.05f
#define NPOW 64
#define TM 8
#define CHK 64
#define APAD 1028
#define KSTR 68   // staged K-chunk row stride in floats (64 + 4 pad)

// ---------------- projections: Q/8, K/8, V ----------------
__global__ __launch_bounds__(256) void proj_kernel(
    const float* __restrict__ x,
    const float* __restrict__ Wq, const float* __restrict__ bq,
    const float* __restrict__ Wk, const float* __restrict__ bk,
    const float* __restrict__ Wv, const float* __restrict__ bv,
    float* __restrict__ qs, float* __restrict__ ks, float* __restrict__ vv)
{
    __shared__ float xs[16][DM];
    int row0 = blockIdx.x * 16;
    int tid = threadIdx.x;
    const float4* xg = (const float4*)(x + (size_t)row0 * DM);
    float4* xs4 = (float4*)&xs[0][0];
    for (int i = tid; i < 16 * DM / 4; i += 256) xs4[i] = xg[i];
    __syncthreads();
    int lane = tid & 63, w = tid >> 6;  // 4 waves, 4 rows each
    float aq[4] = {0,0,0,0}, ak[4] = {0,0,0,0}, av[4] = {0,0,0,0};
    for (int i = 0; i < DM; ++i) {
        float wq = Wq[i*DK + lane], wk = Wk[i*DK + lane], wv = Wv[i*DK + lane];
        #pragma unroll
        for (int r = 0; r < 4; ++r) {
            float xv = xs[w*4 + r][i];
            aq[r] = fmaf(xv, wq, aq[r]);
            ak[r] = fmaf(xv, wk, ak[r]);
            av[r] = fmaf(xv, wv, av[r]);
        }
    }
    float bqv = bq[lane], bkv = bk[lane], bvv = bv[lane];
    #pragma unroll
    for (int r = 0; r < 4; ++r) {
        size_t o = (size_t)(row0 + w*4 + r) * DK + lane;
        qs[o] = (aq[r] + bqv) * 0.125f;
        ks[o] = (ak[r] + bkv) * 0.125f;
        vv[o] = av[r] + bvv;
    }
}

// ---------------- chunk Gram sums (chunk = 32) ----------------
__global__ __launch_bounds__(64) void gram_kernel(
    const float* __restrict__ ks, float* __restrict__ gp)
{
    int bc = blockIdx.x; int b = bc >> 5, c = bc & 31;
    __shared__ float kc[32][DK];
    int lane = threadIdx.x;
    const float* src = ks + ((size_t)b*SS + c*32) * DK;
    for (int i = lane; i < 32*DK; i += 64) ((float*)kc)[i] = src[i];
    __syncthreads();
    float row[DK];
    #pragma unroll
    for (int j = 0; j < DK; ++j) row[j] = 0.f;
    for (int s = 0; s < 32; ++s) {
        float ki = kc[s][lane];
        const float4* kr = (const float4*)&kc[s][0];
        #pragma unroll
        for (int j4 = 0; j4 < 16; ++j4) {
            float4 kv = kr[j4];
            row[4*j4+0] = fmaf(ki, kv.x, row[4*j4+0]);
            row[4*j4+1] = fmaf(ki, kv.y, row[4*j4+1]);
            row[4*j4+2] = fmaf(ki, kv.z, row[4*j4+2]);
            row[4*j4+3] = fmaf(ki, kv.w, row[4*j4+3]);
        }
    }
    float* dst = gp + (((size_t)b*32 + c) * DK + lane) * DK;
    #pragma unroll
    for (int j = 0; j < DK; ++j) dst[j] = row[j];
}

// ---------------- exclusive prefix over chunks ----------------
__global__ __launch_bounds__(256) void prefix_kernel(float* __restrict__ gp)
{
    int b = blockIdx.x; int tid = threadIdx.x;
    float run[16];
    #pragma unroll
    for (int e = 0; e < 16; ++e) run[e] = 0.f;
    for (int c = 0; c < 32; ++c) {
        float* p = gp + ((size_t)b*32 + c) * 4096 + tid * 16;
        #pragma unroll
        for (int e = 0; e < 16; ++e) { float t = p[e]; p[e] = run[e]; run[e] += t; }
    }
}

// ---------------- per-(b,t) top eigenvalue -> eta ----------------
__global__ __launch_bounds__(64) void eigen_kernel(
    const float* __restrict__ ks, const float* __restrict__ gp,
    float* __restrict__ eta)
{
    int bt = blockIdx.x; int b = bt >> 10, t = bt & (SS - 1);
    int c = t >> 5;
    int lane = threadIdx.x;
    __shared__ float kc[32][DK];
    __shared__ float vsh[DK];
    float row[DK];
    const float4* gr = (const float4*)(gp + (((size_t)b*32 + c) * DK + lane) * DK);
    #pragma unroll
    for (int j4 = 0; j4 < 16; ++j4) {
        float4 g = gr[j4];
        row[4*j4] = g.x; row[4*j4+1] = g.y; row[4*j4+2] = g.z; row[4*j4+3] = g.w;
    }
    const float* src = ks + ((size_t)b*SS + c*32) * DK;
    for (int i = lane; i < 32*DK; i += 64) ((float*)kc)[i] = src[i];
    __syncthreads();
    int nrow = t - c*32 + 1;
    for (int s = 0; s < nrow; ++s) {
        float ki = kc[s][lane];
        const float4* kr = (const float4*)&kc[s][0];
        #pragma unroll
        for (int j4 = 0; j4 < 16; ++j4) {
            float4 kv = kr[j4];
            row[4*j4+0] = fmaf(ki, kv.x, row[4*j4+0]);
            row[4*j4+1] = fmaf(ki, kv.y, row[4*j4+1]);
            row[4*j4+2] = fmaf(ki, kv.z, row[4*j4+2]);
            row[4*j4+3] = fmaf(ki, kv.w, row[4*j4+3]);
        }
    }
    // power iteration, v init = ones (y = G*1)
    float y;
    {
        float a0 = 0, a1 = 0, a2 = 0, a3 = 0;
        #pragma unroll
        for (int j = 0; j < DK; j += 4) {
            a0 += row[j]; a1 += row[j+1]; a2 += row[j+2]; a3 += row[j+3];
        }
        y = (a0 + a1) + (a2 + a3);
    }
    for (int it = 0; it < NPOW; ++it) {
        float n = y * y;
        #pragma unroll
        for (int off = 1; off < 64; off <<= 1) n += __shfl_xor(n, off, 64);
        float rn = rsqrtf(fmaxf(n, 1e-30f));
        vsh[lane] = y * rn;
        __syncthreads();
        const float4* vr = (const float4*)vsh;
        float a0 = 0, a1 = 0, a2 = 0, a3 = 0;
        #pragma unroll
        for (int j4 = 0; j4 < 16; ++j4) {
            float4 v4 = vr[j4];
            a0 = fmaf(row[4*j4+0], v4.x, a0);
            a1 = fmaf(row[4*j4+1], v4.y, a1);
            a2 = fmaf(row[4*j4+2], v4.z, a2);
            a3 = fmaf(row[4*j4+3], v4.w, a3);
        }
        y = (a0 + a1) + (a2 + a3);
        __syncthreads();
    }
    float lam = y * vsh[lane];
    #pragma unroll
    for (int off = 1; off < 64; off <<= 1) lam += __shfl_xor(lam, off, 64);
    if (lane == 0) {
        float l = fmaxf(lam, 0.f);
        eta[(size_t)b*SS + t] = 0.9f / (l + 1e-8f);
    }
}

// ---------------- fused ISTA + output projection ----------------
__device__ inline void stage_chunk(float* __restrict__ ksc,
                                   const float* __restrict__ src,
                                   int rows, int tid)
{
    const float4* s4 = (const float4*)src;
    float4* d4 = (float4*)ksc;
    int n4 = rows * 16;
    for (int i = tid; i < n4; i += 256) {
        int row = i >> 4, g = i & 15;
        d4[row * 17 + g] = s4[i];   // stride 17 float4 = 68 floats
    }
}

__global__ __launch_bounds__(256, 2) void ista_kernel(
    const float* __restrict__ qsp, const float* __restrict__ ksp,
    const float* __restrict__ vp, const float* __restrict__ etap,
    float* __restrict__ out)
{
    __shared__ float alpha[TM][APAD];
    __shared__ float ksc[CHK * KSTR];
    __shared__ float Rl[TM][DK];
    __shared__ float qsl[TM][DK];

    int bid = blockIdx.x;
    int b = bid & 7;
    int tile = (SS / TM - 1) - (bid >> 3);   // heavy tiles first
    int t0 = tile * TM;
    int Sact = t0 + TM;
    int tid = threadIdx.x;

    int r1 = tid >> 5;        // mv1/out: 8 rows x 32 k-pair lanes
    int L  = tid & 31;
    int rp  = tid >> 6;       // mv2: rows rp, rp+4 ; 64 s-lanes
    int L64 = tid & 63;

    const float* ksb = ksp + (size_t)b * SS * DK;
    const float* vb  = vp  + (size_t)b * SS * DK;

    float eta0 = etap[(size_t)b*SS + t0 + rp];
    float eta1 = etap[(size_t)b*SS + t0 + rp + 4];
    float thr0 = eta0 * SPARS, thr1 = eta1 * SPARS;
    int tr0 = t0 + rp, tr1 = t0 + rp + 4;

    for (int i = tid; i < TM * APAD; i += 256) ((float*)alpha)[i] = 0.f;
    for (int i = tid; i < TM * DK; i += 256)
        ((float*)qsl)[i] = qsp[((size_t)b*SS + t0) * DK + i];
    __syncthreads();

    for (int it = 0; it < NITER; ++it) {
        // ---- Ka = alpha @ Ks ----
        float ka0a = 0.f, ka0b = 0.f, ka1a = 0.f, ka1b = 0.f;
        for (int cb = 0; cb < Sact; cb += CHK) {
            int cs = min(CHK, Sact - cb);
            __syncthreads();
            stage_chunk(ksc, ksb + (size_t)cb * DK, cs, tid);
            __syncthreads();
            const float* ap = &alpha[r1][cb];
            const float* kp = &ksc[2 * L];
            int sl = 0;
            for (; sl + 2 <= cs; sl += 2) {
                float a0 = ap[sl], a1 = ap[sl + 1];
                float2 k0 = *(const float2*)(kp + (size_t)sl * KSTR);
                float2 k1 = *(const float2*)(kp + (size_t)(sl + 1) * KSTR);
                ka0a = fmaf(a0, k0.x, ka0a);
                ka1a = fmaf(a0, k0.y, ka1a);
                ka0b = fmaf(a1, k1.x, ka0b);
                ka1b = fmaf(a1, k1.y, ka1b);
            }
            for (; sl < cs; ++sl) {
                float a0 = ap[sl];
                float2 k0 = *(const float2*)(kp + (size_t)sl * KSTR);
                ka0a = fmaf(a0, k0.x, ka0a);
                ka1a = fmaf(a0, k0.y, ka1a);
            }
        }
        Rl[r1][2*L]   = (ka0a + ka0b) - qsl[r1][2*L];
        Rl[r1][2*L+1] = (ka1a + ka1b) - qsl[r1][2*L+1];
        __syncthreads();

        float Rr0[DK], Rr1[DK];
        {
            const float4* p0 = (const float4*)&Rl[rp][0];
            const float4* p1 = (const float4*)&Rl[rp + 4][0];
            #pragma unroll
            for (int j = 0; j < 16; ++j) {
                float4 a = p0[j]; float4 c = p1[j];
                Rr0[4*j] = a.x; Rr0[4*j+1] = a.y; Rr0[4*j+2] = a.z; Rr0[4*j+3] = a.w;
                Rr1[4*j] = c.x; Rr1[4*j+1] = c.y; Rr1[4*j+2] = c.z; Rr1[4*j+3] = c.w;
            }
        }

        // ---- grad + shrink-update ----
        for (int cb = 0; cb < Sact; cb += CHK) {
            int cs = min(CHK, Sact - cb);
            __syncthreads();
            stage_chunk(ksc, ksb + (size_t)cb * DK, cs, tid);
            __syncthreads();
            if (L64 < cs) {
                int s = cb + L64;
                const float* kp = &ksc[(size_t)L64 * KSTR];
                float g0a=0,g0b=0,g0c=0,g0d=0, g1a=0,g1b=0,g1c=0,g1d=0;
                #pragma unroll
                for (int j = 0; j < 16; ++j) {
                    float4 kv = *(const float4*)(kp + 4 * j);
                    g0a = fmaf(kv.x, Rr0[4*j],   g0a);
                    g0b = fmaf(kv.y, Rr0[4*j+1], g0b);
                    g0c = fmaf(kv.z, Rr0[4*j+2], g0c);
                    g0d = fmaf(kv.w, Rr0[4*j+3], g0d);
                    g1a = fmaf(kv.x, Rr1[4*j],   g1a);
                    g1b = fmaf(kv.y, Rr1[4*j+1], g1b);
                    g1c = fmaf(kv.z, Rr1[4*j+2], g1c);
                    g1d = fmaf(kv.w, Rr1[4*j+3], g1d);
                }
                float grad0 = (g0a + g0b) + (g0c + g0d);
                float grad1 = (g1a + g1b) + (g1c + g1d);
                if (s <= tr0) {
                    float a_old = alpha[rp][s];
                    float z = fmaf(-eta0, grad0, a_old);
                    float az = fabsf(z) - thr0;
                    alpha[rp][s] = az > 0.f ? copysignf(az, z) : 0.f;
                }
                if (s <= tr1) {
                    float a_old = alpha[rp + 4][s];
                    float z = fmaf(-eta1, grad1, a_old);
                    float az = fabsf(z) - thr1;
                    alpha[rp + 4][s] = az > 0.f ? copysignf(az, z) : 0.f;
                }
            }
        }
    }

    // ---- out = alpha @ V ----
    float o0a = 0.f, o0b = 0.f, o1a = 0.f, o1b = 0.f;
    for (int cb = 0; cb < Sact; cb += CHK) {
        int cs = min(CHK, Sact - cb);
        __syncthreads();
        stage_chunk(ksc, vb + (size_t)cb * DK, cs, tid);
        __syncthreads();
        const float* ap = &alpha[r1][cb];
        const float* kp = &ksc[2 * L];
        int sl = 0;
        for (; sl + 2 <= cs; sl += 2) {
            float a0 = ap[sl], a1 = ap[sl + 1];
            float2 k0 = *(const float2*)(kp + (size_t)sl * KSTR);
            float2 k1 = *(const float2*)(kp + (size_t)(sl + 1) * KSTR);
            o0a = fmaf(a0, k0.x, o0a);
            o1a = fmaf(a0, k0.y, o1a);
            o0b = fmaf(a1, k1.x, o0b);
            o1b = fmaf(a1, k1.y, o1b);
        }
        for (; sl < cs; ++sl) {
            float a0 = ap[sl];
            float2 k0 = *(const float2*)(kp + (size_t)sl * KSTR);
            o0a = fmaf(a0, k0.x, o0a);
            o1a = fmaf(a0, k0.y, o1a);
        }
    }
    size_t oo = ((size_t)b * SS + t0 + r1) * DK + 2 * L;
    float2 ov = make_float2(o0a + o0b, o1a + o1b);
    *(float2*)&out[oo] = ov;
}

extern "C" void kernel_launch(void* const* d_in, const int* in_sizes, int n_in,
                              void* d_out, int out_size, void* d_ws, size_t ws_size,
                              hipStream_t stream)
{
    const float* x  = (const float*)d_in[0];
    const float* Wq = (const float*)d_in[1];
    const float* bq = (const float*)d_in[2];
    const float* Wk = (const float*)d_in[3];
    const float* bk = (const float*)d_in[4];
    const float* Wv = (const float*)d_in[5];
    const float* bv = (const float*)d_in[6];
    float* out = (float*)d_out;

    float* w  = (float*)d_ws;
    float* qs = w;
    float* ks = w + (size_t)BB * SS * DK;
    float* v  = w + (size_t)2 * BB * SS * DK;
    float* gp = w + (size_t)3 * BB * SS * DK;           // [B][32][64][64]
    float* eta = gp + (size_t)BB * 32 * DK * DK;        // [B][S]

    hipLaunchKernelGGL(proj_kernel, dim3(BB * SS / 16), dim3(256), 0, stream,
                       x, Wq, bq, Wk, bk, Wv, bv, qs, ks, v);
    hipLaunchKernelGGL(gram_kernel, dim3(BB * 32), dim3(64), 0, stream, ks, gp);
    hipLaunchKernelGGL(prefix_kernel, dim3(BB), dim3(256), 0, stream, gp);
    hipLaunchKernelGGL(eigen_kernel, dim3(BB * SS), dim3(64), 0, stream, ks, gp, eta);
    hipLaunchKernelGGL(ista_kernel, dim3(BB * SS / TM), dim3(256), 0, stream,
                       qs, ks, v, eta, out);
}

// Round 5
// 1538.193 us; speedup vs baseline: 1.7322x; 1.7322x over previous
//
#include <hip/hip_runtime.h>
#include <math.h>

#define BB 8
#define SS 1024
#define DM 512
#define DK 64
#define NITER 40
#define SPARS 0.05f
#define NPOW 64
#define TM 8
#define CHK 32
#define APAD 1028

// ---------------- projections: Q/8, K/8, V ----------------
__global__ __launch_bounds__(256) void proj_kernel(
    const float* __restrict__ x,
    const float* __restrict__ Wq, const float* __restrict__ bq,
    const float* __restrict__ Wk, const float* __restrict__ bk,
    const float* __restrict__ Wv, const float* __restrict__ bv,
    float* __restrict__ qs, float* __restrict__ ks, float* __restrict__ vv)
{
    __shared__ float xs[16][DM];
    int row0 = blockIdx.x * 16;
    int tid = threadIdx.x;
    const float4* xg = (const float4*)(x + (size_t)row0 * DM);
    float4* xs4 = (float4*)&xs[0][0];
    for (int i = tid; i < 16 * DM / 4; i += 256) xs4[i] = xg[i];
    __syncthreads();
    int lane = tid & 63, w = tid >> 6;  // 4 waves, 4 rows each
    float aq[4] = {0,0,0,0}, ak[4] = {0,0,0,0}, av[4] = {0,0,0,0};
    for (int i = 0; i < DM; ++i) {
        float wq = Wq[i*DK + lane], wk = Wk[i*DK + lane], wv = Wv[i*DK + lane];
        #pragma unroll
        for (int r = 0; r < 4; ++r) {
            float xv = xs[w*4 + r][i];
            aq[r] = fmaf(xv, wq, aq[r]);
            ak[r] = fmaf(xv, wk, ak[r]);
            av[r] = fmaf(xv, wv, av[r]);
        }
    }
    float bqv = bq[lane], bkv = bk[lane], bvv = bv[lane];
    #pragma unroll
    for (int r = 0; r < 4; ++r) {
        size_t o = (size_t)(row0 + w*4 + r) * DK + lane;
        qs[o] = (aq[r] + bqv) * 0.125f;
        ks[o] = (ak[r] + bkv) * 0.125f;
        vv[o] = av[r] + bvv;
    }
}

// ---------------- chunk Gram sums (chunk = 32) ----------------
__global__ __launch_bounds__(64) void gram_kernel(
    const float* __restrict__ ks, float* __restrict__ gp)
{
    int bc = blockIdx.x; int b = bc >> 5, c = bc & 31;
    __shared__ float kc[32][DK];
    int lane = threadIdx.x;
    const float* src = ks + ((size_t)b*SS + c*32) * DK;
    for (int i = lane; i < 32*DK; i += 64) ((float*)kc)[i] = src[i];
    __syncthreads();
    float row[DK];
    #pragma unroll
    for (int j = 0; j < DK; ++j) row[j] = 0.f;
    for (int s = 0; s < 32; ++s) {
        float ki = kc[s][lane];
        const float4* kr = (const float4*)&kc[s][0];
        #pragma unroll
        for (int j4 = 0; j4 < 16; ++j4) {
            float4 kv = kr[j4];
            row[4*j4+0] = fmaf(ki, kv.x, row[4*j4+0]);
            row[4*j4+1] = fmaf(ki, kv.y, row[4*j4+1]);
            row[4*j4+2] = fmaf(ki, kv.z, row[4*j4+2]);
            row[4*j4+3] = fmaf(ki, kv.w, row[4*j4+3]);
        }
    }
    float* dst = gp + (((size_t)b*32 + c) * DK + lane) * DK;
    #pragma unroll
    for (int j = 0; j < DK; ++j) dst[j] = row[j];
}

// ---------------- exclusive prefix over chunks ----------------
__global__ __launch_bounds__(256) void prefix_kernel(float* __restrict__ gp)
{
    int b = blockIdx.x; int tid = threadIdx.x;
    float run[16];
    #pragma unroll
    for (int e = 0; e < 16; ++e) run[e] = 0.f;
    for (int c = 0; c < 32; ++c) {
        float* p = gp + ((size_t)b*32 + c) * 4096 + tid * 16;
        #pragma unroll
        for (int e = 0; e < 16; ++e) { float t = p[e]; p[e] = run[e]; run[e] += t; }
    }
}

// ---------------- per-(b,t) top eigenvalue -> eta ----------------
__global__ __launch_bounds__(64) void eigen_kernel(
    const float* __restrict__ ks, const float* __restrict__ gp,
    float* __restrict__ eta)
{
    int bt = blockIdx.x; int b = bt >> 10, t = bt & (SS - 1);
    int c = t >> 5;
    int lane = threadIdx.x;
    __shared__ float kc[32][DK];
    __shared__ float vsh[DK];
    float row[DK];
    const float4* gr = (const float4*)(gp + (((size_t)b*32 + c) * DK + lane) * DK);
    #pragma unroll
    for (int j4 = 0; j4 < 16; ++j4) {
        float4 g = gr[j4];
        row[4*j4] = g.x; row[4*j4+1] = g.y; row[4*j4+2] = g.z; row[4*j4+3] = g.w;
    }
    const float* src = ks + ((size_t)b*SS + c*32) * DK;
    for (int i = lane; i < 32*DK; i += 64) ((float*)kc)[i] = src[i];
    __syncthreads();
    int nrow = t - c*32 + 1;
    for (int s = 0; s < nrow; ++s) {
        float ki = kc[s][lane];
        const float4* kr = (const float4*)&kc[s][0];
        #pragma unroll
        for (int j4 = 0; j4 < 16; ++j4) {
            float4 kv = kr[j4];
            row[4*j4+0] = fmaf(ki, kv.x, row[4*j4+0]);
            row[4*j4+1] = fmaf(ki, kv.y, row[4*j4+1]);
            row[4*j4+2] = fmaf(ki, kv.z, row[4*j4+2]);
            row[4*j4+3] = fmaf(ki, kv.w, row[4*j4+3]);
        }
    }
    // power iteration, v init = ones (y = G*1)
    float y;
    {
        float a0 = 0, a1 = 0, a2 = 0, a3 = 0;
        #pragma unroll
        for (int j = 0; j < DK; j += 4) {
            a0 += row[j]; a1 += row[j+1]; a2 += row[j+2]; a3 += row[j+3];
        }
        y = (a0 + a1) + (a2 + a3);
    }
    for (int it = 0; it < NPOW; ++it) {
        float n = y * y;
        #pragma unroll
        for (int off = 1; off < 64; off <<= 1) n += __shfl_xor(n, off, 64);
        float rn = rsqrtf(fmaxf(n, 1e-30f));
        vsh[lane] = y * rn;
        __syncthreads();
        const float4* vr = (const float4*)vsh;
        float a0 = 0, a1 = 0, a2 = 0, a3 = 0;
        #pragma unroll
        for (int j4 = 0; j4 < 16; ++j4) {
            float4 v4 = vr[j4];
            a0 = fmaf(row[4*j4+0], v4.x, a0);
            a1 = fmaf(row[4*j4+1], v4.y, a1);
            a2 = fmaf(row[4*j4+2], v4.z, a2);
            a3 = fmaf(row[4*j4+3], v4.w, a3);
        }
        y = (a0 + a1) + (a2 + a3);
        __syncthreads();
    }
    float lam = y * vsh[lane];
    #pragma unroll
    for (int off = 1; off < 64; off <<= 1) lam += __shfl_xor(lam, off, 64);
    if (lane == 0) {
        float l = fmaxf(lam, 0.f);
        eta[(size_t)b*SS + t] = 0.9f / (l + 1e-8f);
    }
}

// ---------------- fused ISTA + output projection (single-sweep, delta-Ka) --------
// Per iteration: ONE sweep over K chunks. grad+shrink uses register-resident R
// (constant within the sweep); delta-alpha is folded into register Ka partials
// while the chunk is staged. Eliminates the old mv1 pass (8x LDS amplification).
__global__ __launch_bounds__(256, 3) void ista_kernel(
    const float* __restrict__ qsp, const float* __restrict__ ksp,
    const float* __restrict__ vp, const float* __restrict__ etap,
    float* __restrict__ out)
{
    __shared__ float  alpha[TM][APAD];     // 32896 B
    __shared__ float4 ksc[CHK * 17];       //  8704 B (16 f4 + 1 pad per row)
    __shared__ float  Dl[TM][33];          //  1056 B
    __shared__ float4 Kl[2][TM][16];       //  4096 B
    __shared__ float4 Kaold[TM][16];       //  2048 B
    __shared__ float4 qsl4[TM][16];        //  2048 B   total ~50.8 KB -> 3 blk/CU

    int bid = blockIdx.x;
    int b = bid & 7;
    int tile = (SS / TM - 1) - (bid >> 3);   // heavy tiles first
    int t0 = tile * TM;
    int Sact = t0 + TM;
    int nc = (Sact + CHK - 1) >> 5;          // chunks of 32
    int tid = threadIdx.x;

    // grad role: 8 row-groups x 32 s-lanes
    int rg = tid >> 5, sl = tid & 31;
    // accum role: half x row x float4-col
    int sh = tid >> 7, ra = (tid >> 4) & 7, c4 = tid & 15;
    int sh16 = sh * 16;

    const float* ksb = ksp + (size_t)b * SS * DK;
    const float* vb  = vp  + (size_t)b * SS * DK;

    float eta_r = etap[(size_t)b*SS + t0 + rg];
    float thr_r = eta_r * SPARS;
    int trow = t0 + rg;

    for (int i = tid; i < TM * APAD; i += 256) ((float*)alpha)[i] = 0.f;
    if (tid < 128) {
        int r = tid >> 4, q = tid & 15;
        qsl4[r][q] = ((const float4*)(qsp + ((size_t)b*SS + t0) * DK))[tid];
        Kaold[r][q] = make_float4(0.f, 0.f, 0.f, 0.f);
    }
    __syncthreads();

    for (int it = 0; it < NITER; ++it) {
        // R for this sweep (held in VGPRs; Ka/qs stable during sweep)
        float Rr[64];
        #pragma unroll
        for (int j4 = 0; j4 < 16; ++j4) {
            float4 ka = Kaold[rg][j4];
            float4 q  = qsl4[rg][j4];
            Rr[4*j4+0] = ka.x - q.x;
            Rr[4*j4+1] = ka.y - q.y;
            Rr[4*j4+2] = ka.z - q.z;
            Rr[4*j4+3] = ka.w - q.w;
        }
        float4 kacc = make_float4(0.f, 0.f, 0.f, 0.f);
        bool last = (it == NITER - 1);

        for (int c = 0, cb = 0; c < nc; ++c, cb += CHK) {
            __syncthreads();
            // ---- stage K chunk (512 float4, 2 per thread) ----
            {
                const float4* s4 = (const float4*)(ksb + (size_t)cb * DK);
                int i1 = tid + 256;
                ksc[(tid >> 4) * 17 + (tid & 15)] = s4[tid];
                ksc[(i1 >> 4) * 17 + (i1 & 15)] = s4[i1];
            }
            __syncthreads();
            // ---- grad + shrink -> alpha, Dl ----
            {
                int s = cb + sl;
                const float4* kr = &ksc[sl * 17];
                float g0 = 0, g1 = 0, g2 = 0, g3 = 0;
                #pragma unroll
                for (int j4 = 0; j4 < 16; ++j4) {
                    float4 kv = kr[j4];
                    g0 = fmaf(kv.x, Rr[4*j4+0], g0);
                    g1 = fmaf(kv.y, Rr[4*j4+1], g1);
                    g2 = fmaf(kv.z, Rr[4*j4+2], g2);
                    g3 = fmaf(kv.w, Rr[4*j4+3], g3);
                }
                float grad = (g0 + g1) + (g2 + g3);
                float dnew = 0.f;
                if (s <= trow) {
                    float a_old = alpha[rg][s];
                    float z = fmaf(-eta_r, grad, a_old);
                    float az = fabsf(z) - thr_r;
                    float an = az > 0.f ? copysignf(az, z) : 0.f;
                    alpha[rg][s] = an;
                    dnew = an - a_old;
                }
                Dl[rg][sl] = dnew;
            }
            if (!last) {
                __syncthreads();
                // ---- accum: Ka partial += Dl * K ----
                #pragma unroll
                for (int k = 0; k < 16; ++k) {
                    int s = sh16 + k;
                    float d = Dl[ra][s];
                    float4 kv = ksc[s * 17 + c4];
                    kacc.x = fmaf(d, kv.x, kacc.x);
                    kacc.y = fmaf(d, kv.y, kacc.y);
                    kacc.z = fmaf(d, kv.z, kacc.z);
                    kacc.w = fmaf(d, kv.w, kacc.w);
                }
            }
        }
        if (!last) {
            Kl[sh][ra][c4] = kacc;
            __syncthreads();
            if (tid < 128) {
                int r = tid >> 4, q = tid & 15;
                float4 a = Kaold[r][q];
                float4 p = Kl[0][r][q], o = Kl[1][r][q];
                a.x += p.x + o.x; a.y += p.y + o.y;
                a.z += p.z + o.z; a.w += p.w + o.w;
                Kaold[r][q] = a;
            }
            __syncthreads();
        }
    }

    // ---- out = alpha @ V (same accum layout) ----
    float4 oacc = make_float4(0.f, 0.f, 0.f, 0.f);
    for (int c = 0, cb = 0; c < nc; ++c, cb += CHK) {
        __syncthreads();
        {
            const float4* s4 = (const float4*)(vb + (size_t)cb * DK);
            int i1 = tid + 256;
            ksc[(tid >> 4) * 17 + (tid & 15)] = s4[tid];
            ksc[(i1 >> 4) * 17 + (i1 & 15)] = s4[i1];
        }
        __syncthreads();
        #pragma unroll
        for (int k = 0; k < 16; ++k) {
            int s = sh16 + k;
            float a = alpha[ra][cb + s];
            float4 vv4 = ksc[s * 17 + c4];
            oacc.x = fmaf(a, vv4.x, oacc.x);
            oacc.y = fmaf(a, vv4.y, oacc.y);
            oacc.z = fmaf(a, vv4.z, oacc.z);
            oacc.w = fmaf(a, vv4.w, oacc.w);
        }
    }
    Kl[sh][ra][c4] = oacc;
    __syncthreads();
    if (tid < 128) {
        int r = tid >> 4, q = tid & 15;
        float4 p = Kl[0][r][q], o = Kl[1][r][q];
        float4 res = make_float4(p.x + o.x, p.y + o.y, p.z + o.z, p.w + o.w);
        ((float4*)(out + ((size_t)b*SS + t0 + r) * DK))[q] = res;
    }
}

extern "C" void kernel_launch(void* const* d_in, const int* in_sizes, int n_in,
                              void* d_out, int out_size, void* d_ws, size_t ws_size,
                              hipStream_t stream)
{
    const float* x  = (const float*)d_in[0];
    const float* Wq = (const float*)d_in[1];
    const float* bq = (const float*)d_in[2];
    const float* Wk = (const float*)d_in[3];
    const float* bk = (const float*)d_in[4];
    const float* Wv = (const float*)d_in[5];
    const float* bv = (const float*)d_in[6];
    float* out = (float*)d_out;

    float* w  = (float*)d_ws;
    float* qs = w;
    float* ks = w + (size_t)BB * SS * DK;
    float* v  = w + (size_t)2 * BB * SS * DK;
    float* gp = w + (size_t)3 * BB * SS * DK;           // [B][32][64][64]
    float* eta = gp + (size_t)BB * 32 * DK * DK;        // [B][S]

    hipLaunchKernelGGL(proj_kernel, dim3(BB * SS / 16), dim3(256), 0, stream,
                       x, Wq, bq, Wk, bk, Wv, bv, qs, ks, v);
    hipLaunchKernelGGL(gram_kernel, dim3(BB * 32), dim3(64), 0, stream, ks, gp);
    hipLaunchKernelGGL(prefix_kernel, dim3(BB), dim3(256), 0, stream, gp);
    hipLaunchKernelGGL(eigen_kernel, dim3(BB * SS), dim3(64), 0, stream, ks, gp, eta);
    hipLaunchKernelGGL(ista_kernel, dim3(BB * SS / TM), dim3(256), 0, stream,
                       qs, ks, v, eta, out);
}